// Round 3
// baseline (298.239 us; speedup 1.0000x reference)
//
#include <hip/hip_runtime.h>
#include <math.h>

#define TYPE_N 5
#define D 256
#define EPS 1e-6f
#define NCOPY 16

// ws layout (float offsets):
//   [0, 20480)        sums_partial[NCOPY][TYPE_N][D]
//   [20480, 20560)    counts_partial[NCOPY][TYPE_N]
//   [20560, 21840)    center[TYPE_N][D]          (raw)
//   [21840, 21845)    counts_final[TYPE_N]
//   [21845, 21925)    dsum_partial[NCOPY][TYPE_N]
//   [21925, 23205)    cme[TYPE_N][D]             (center - EPS, for k3)
#define OFF_CNTP   (NCOPY * TYPE_N * D)          // 20480
#define OFF_CENTER (OFF_CNTP + NCOPY * TYPE_N)   // 20560
#define OFF_CNTF   (OFF_CENTER + TYPE_N * D)     // 21840
#define OFF_DSUM   (OFF_CNTF + TYPE_N)           // 21845
#define OFF_CME    (OFF_DSUM + NCOPY * TYPE_N)   // 21925
#define WS_FLOATS  (OFF_CME + TYPE_N * D)        // 23205

__device__ __forceinline__ int argmax5(const float* __restrict__ yr) {
    int lab = 0;
    float best = yr[0];
    #pragma unroll
    for (int c = 1; c < TYPE_N; ++c) {
        float v = yr[c];
        if (v > best) { best = v; lab = c; }
    }
    return lab;
}

// --- K1: per-class counts + centroid column sums ----------------------------
// Row-per-wave, 8 rows in flight, no cross-lane ops, no divergence.
__global__ __launch_bounds__(256) void k1_sums(const float* __restrict__ x,
                                               const float* __restrict__ y,
                                               float* __restrict__ ws, int N) {
    __shared__ float lsum[4][TYPE_N][D];   // 20 KB
    const int lane = threadIdx.x & 63;
    const int wid  = threadIdx.x >> 6;
    const int wave = blockIdx.x * 4 + wid;
    const int nw   = gridDim.x * 4;

    float acc[TYPE_N][4] = {};
    float cnt[TYPE_N] = {};
    const float cw = (lane == 0) ? 1.0f : 0.0f;  // lane0 carries counts

    for (int r0 = wave * 8; r0 < N; r0 += nw * 8) {
        if (r0 + 8 <= N) {
            // phase 1: issue ALL loads (independent; 8 float4 + 40 scalars in flight)
            float  yv[8][TYPE_N];
            float4 v[8];
            #pragma unroll
            for (int j = 0; j < 8; ++j) {
                const float* yr = y + (size_t)(r0 + j) * TYPE_N;
                #pragma unroll
                for (int k = 0; k < TYPE_N; ++k) yv[j][k] = yr[k];
                v[j] = *reinterpret_cast<const float4*>(
                    x + (size_t)(r0 + j) * D + lane * 4);
            }
            // phase 2: pure VALU — argmax + branchless class accumulate
            #pragma unroll
            for (int j = 0; j < 8; ++j) {
                int lab = 0; float best = yv[j][0];
                #pragma unroll
                for (int k = 1; k < TYPE_N; ++k) {
                    if (yv[j][k] > best) { best = yv[j][k]; lab = k; }
                }
                #pragma unroll
                for (int c = 0; c < TYPE_N; ++c) {
                    const float m = (lab == c) ? 1.0f : 0.0f;
                    acc[c][0] = fmaf(m, v[j].x, acc[c][0]);
                    acc[c][1] = fmaf(m, v[j].y, acc[c][1]);
                    acc[c][2] = fmaf(m, v[j].z, acc[c][2]);
                    acc[c][3] = fmaf(m, v[j].w, acc[c][3]);
                    cnt[c]    = fmaf(m, cw, cnt[c]);
                }
            }
        } else {
            for (int j = 0; j < N - r0; ++j) {
                const int lab = argmax5(y + (size_t)(r0 + j) * TYPE_N);
                const float4 vv = *reinterpret_cast<const float4*>(
                    x + (size_t)(r0 + j) * D + lane * 4);
                #pragma unroll
                for (int c = 0; c < TYPE_N; ++c) {
                    const float m = (lab == c) ? 1.0f : 0.0f;
                    acc[c][0] = fmaf(m, vv.x, acc[c][0]);
                    acc[c][1] = fmaf(m, vv.y, acc[c][1]);
                    acc[c][2] = fmaf(m, vv.z, acc[c][2]);
                    acc[c][3] = fmaf(m, vv.w, acc[c][3]);
                    cnt[c]    = fmaf(m, cw, cnt[c]);
                }
            }
        }
    }

    #pragma unroll
    for (int c = 0; c < TYPE_N; ++c)
        *reinterpret_cast<float4*>(&lsum[wid][c][lane * 4]) =
            make_float4(acc[c][0], acc[c][1], acc[c][2], acc[c][3]);

    // lane0 of each wave holds this wave's full per-class count
    if (lane == 0) {
        #pragma unroll
        for (int c = 0; c < TYPE_N; ++c)
            atomicAdd(&ws[OFF_CNTP + (blockIdx.x % NCOPY) * TYPE_N + c], cnt[c]);
    }

    __syncthreads();
    const int t = threadIdx.x;
    float* sums = ws + (size_t)(blockIdx.x % NCOPY) * (TYPE_N * D);
    #pragma unroll
    for (int c = 0; c < TYPE_N; ++c) {
        float s = lsum[0][c][t] + lsum[1][c][t] + lsum[2][c][t] + lsum[3][c][t];
        atomicAdd(&sums[c * D + t], s);
    }
}

// --- K2: reduce copies -> centers (raw + eps-folded) ------------------------
__global__ __launch_bounds__(256) void k2_center(float* __restrict__ ws) {
    const int t = threadIdx.x;  // column 0..255
    float cnts[TYPE_N];
    #pragma unroll
    for (int c = 0; c < TYPE_N; ++c) {
        float s = 0.f;
        #pragma unroll
        for (int p = 0; p < NCOPY; ++p) s += ws[OFF_CNTP + p * TYPE_N + c];
        cnts[c] = s;
    }
    float* center = ws + OFF_CENTER;
    float* cme    = ws + OFF_CME;
    #pragma unroll
    for (int c = 0; c < TYPE_N; ++c) {
        float s = 0.f;
        #pragma unroll
        for (int p = 0; p < NCOPY; ++p) s += ws[p * TYPE_N * D + c * D + t];
        float sc = fmaxf(cnts[c], 1.0f);
        float ctr = (cnts[c] > 0.f) ? s / sc : 0.f;
        center[c * D + t] = ctr;
        cme[c * D + t]    = ctr - EPS;   // so diff = x - cme (eps folded)
    }
    if (t < TYPE_N) ws[OFF_CNTF + t] = cnts[t];
}

// --- K3: row-per-lane distance to own centroid ------------------------------
__global__ __launch_bounds__(256) void k3_dist(const float* __restrict__ x,
                                               const float* __restrict__ y,
                                               float* __restrict__ ws, int N) {
    __shared__ float lds[4][TYPE_N];
    const int lane = threadIdx.x & 63;
    const int wid  = threadIdx.x >> 6;
    const int r = blockIdx.x * 256 + threadIdx.x;

    int lab = 0;
    float d = 0.f;
    if (r < N) {
        lab = argmax5(y + (size_t)r * TYPE_N);
        const float4* xr = reinterpret_cast<const float4*>(x + (size_t)r * D);
        const float4* cr = reinterpret_cast<const float4*>(ws + OFF_CME + lab * D);
        float ss[4] = {0.f, 0.f, 0.f, 0.f};
        #pragma unroll 8
        for (int i = 0; i < 64; ++i) {
            const float4 a = xr[i];
            const float4 b = cr[i];
            const float t0 = a.x - b.x;
            const float t1 = a.y - b.y;
            const float t2 = a.z - b.z;
            const float t3 = a.w - b.w;
            float s = fmaf(t0, t0, t1 * t1);
            s = fmaf(t2, t2, s);
            s = fmaf(t3, t3, s);
            ss[i & 3] += s;
        }
        d = sqrtf(ss[0] + ss[1] + ss[2] + ss[3]);
    }

    #pragma unroll
    for (int c = 0; c < TYPE_N; ++c) {
        float v = (lab == c) ? d : 0.f;
        #pragma unroll
        for (int off = 32; off > 0; off >>= 1) v += __shfl_xor(v, off);
        if (lane == 0) lds[wid][c] = v;
    }
    __syncthreads();
    if (threadIdx.x < TYPE_N) {
        float s = lds[0][threadIdx.x] + lds[1][threadIdx.x] +
                  lds[2][threadIdx.x] + lds[3][threadIdx.x];
        atomicAdd(&ws[OFF_DSUM + (blockIdx.x % NCOPY) * TYPE_N + threadIdx.x], s);
    }
}

// --- K4: scalar epilogue -----------------------------------------------------
__global__ __launch_bounds__(64) void k4_final(const float* __restrict__ ws,
                                               float* __restrict__ out) {
    const int lane = threadIdx.x;  // 0..63
    const float* center = ws + OFF_CENTER;
    const float* counts = ws + OFF_CNTF;
    const float* dsp    = ws + OFF_DSUM;

    float csum[TYPE_N];
    #pragma unroll
    for (int c = 0; c < TYPE_N; ++c) {
        float s = 0.f;
        #pragma unroll
        for (int k = 0; k < 4; ++k) s += center[c * D + lane * 4 + k];
        #pragma unroll
        for (int off = 32; off > 0; off >>= 1) s += __shfl_xor(s, off);
        csum[c] = s;
    }

    float cnts[TYPE_N], dsum[TYPE_N];
    bool present[TYPE_N];
    float real_n = 0.f;
    #pragma unroll
    for (int c = 0; c < TYPE_N; ++c) {
        cnts[c] = counts[c];
        float s = 0.f;
        #pragma unroll
        for (int p = 0; p < NCOPY; ++p) s += dsp[p * TYPE_N + c];
        dsum[c] = s;
        present[c] = (cnts[c] > 0.f) && (csum[c] != 0.f);
        real_n += present[c] ? 1.f : 0.f;
    }

    float loss_pos = 0.f;
    #pragma unroll
    for (int c = 0; c < TYPE_N; ++c) {
        float pcm = dsum[c] / fmaxf(cnts[c], 1.f);
        loss_pos += present[c] ? pcm : 0.f;
    }
    loss_pos = (real_n > 0.f) ? loss_pos / fmaxf(real_n, 1.f) : 1.0f;

    float pairsum = 0.f;
    #pragma unroll
    for (int i = 0; i < TYPE_N; ++i) {
        #pragma unroll
        for (int j = i + 1; j < TYPE_N; ++j) {
            float s = 0.f;
            #pragma unroll
            for (int k = 0; k < 4; ++k) {
                float dd = center[i * D + lane * 4 + k] - center[j * D + lane * 4 + k] + EPS;
                s += dd * dd;
            }
            #pragma unroll
            for (int off = 32; off > 0; off >>= 1) s += __shfl_xor(s, off);
            float pd = sqrtf(s);
            pairsum += (present[i] && present[j]) ? pd : 0.f;
        }
    }
    float n_pairs = real_n * (real_n - 1.f) * 0.5f;
    float loss_neg = (real_n > 1.f) ? pairsum / fmaxf(n_pairs, 1.f) : 0.f;

    if (lane == 0) out[0] = loss_pos / (loss_neg + loss_pos);
}

extern "C" void kernel_launch(void* const* d_in, const int* in_sizes, int n_in,
                              void* d_out, int out_size, void* d_ws, size_t ws_size,
                              hipStream_t stream) {
    const float* x = (const float*)d_in[0];
    const float* y = (const float*)d_in[1];
    float* out = (float*)d_out;
    float* ws  = (float*)d_ws;
    const int N = in_sizes[0] / D;  // 200000

    hipMemsetAsync(d_ws, 0, (size_t)WS_FLOATS * sizeof(float), stream);

    k1_sums<<<2048, 256, 0, stream>>>(x, y, ws, N);
    k2_center<<<1, 256, 0, stream>>>(ws);
    const int grid3 = (N + 255) / 256;  // one row per thread
    k3_dist<<<grid3, 256, 0, stream>>>(x, y, ws, N);
    k4_final<<<1, 64, 0, stream>>>(ws, out);
}

// Round 4
// 200.056 us; speedup vs baseline: 1.4908x; 1.4908x over previous
//
#include <hip/hip_runtime.h>
#include <math.h>

#define TYPE_N 5
#define D 256
#define EPS 1e-6f
#define NCOPY 16

// ws layout (float offsets):
//   [0, 20480)        sums_partial[NCOPY][TYPE_N][D]
//   [20480, 20560)    counts_partial[NCOPY][TYPE_N]
//   [20560, 21840)    center[TYPE_N][D]          (raw)
//   [21840, 21845)    counts_final[TYPE_N]
//   [21845, 21925)    dsum_partial[NCOPY][TYPE_N]
//   [21925, 23205)    cme[TYPE_N][D]             (center - EPS, for k3)
#define OFF_CNTP   (NCOPY * TYPE_N * D)          // 20480
#define OFF_CENTER (OFF_CNTP + NCOPY * TYPE_N)   // 20560
#define OFF_CNTF   (OFF_CENTER + TYPE_N * D)     // 21840
#define OFF_DSUM   (OFF_CNTF + TYPE_N)           // 21845
#define OFF_CME    (OFF_DSUM + NCOPY * TYPE_N)   // 21925
#define WS_FLOATS  (OFF_CME + TYPE_N * D)        // 23205

__device__ __forceinline__ int argmax5(const float* __restrict__ yr) {
    int lab = 0;
    float best = yr[0];
    #pragma unroll
    for (int c = 1; c < TYPE_N; ++c) {
        float v = yr[c];
        if (v > best) { best = v; lab = c; }
    }
    return lab;
}

// --- K1: per-class counts + centroid column sums ----------------------------
// Block owns a contiguous row slab. Phase A: labels -> LDS (+counts).
// Phase B: k3-style streaming, 8 float4 loads in flight per wave.
__global__ __launch_bounds__(256, 4) void k1_sums(const float* __restrict__ x,
                                                  const float* __restrict__ y,
                                                  float* __restrict__ ws,
                                                  int N, int rpb) {
    __shared__ float lsum[4][TYPE_N][D];   // 20 KB
    __shared__ int   labs[256];
    const int lane = threadIdx.x & 63;
    const int wid  = threadIdx.x >> 6;
    const int r0   = blockIdx.x * rpb;
    const int rows = (N - r0 < rpb) ? (N - r0) : rpb;
    if (rows <= 0) return;  // whole block exits together (before any sync)

    // Phase A: one label per thread, counts via wave butterfly
    {
        const int j = threadIdx.x;
        float cnt[TYPE_N] = {};
        if (j < rows) {
            const int lab = argmax5(y + (size_t)(r0 + j) * TYPE_N);
            labs[j] = lab;
            #pragma unroll
            for (int c = 0; c < TYPE_N; ++c) cnt[c] = (lab == c) ? 1.0f : 0.0f;
        }
        #pragma unroll
        for (int c = 0; c < TYPE_N; ++c) {
            float v = cnt[c];
            #pragma unroll
            for (int off = 32; off > 0; off >>= 1) v += __shfl_xor(v, off);
            if (lane == 0)
                atomicAdd(&ws[OFF_CNTP + (blockIdx.x % NCOPY) * TYPE_N + c], v);
        }
    }
    __syncthreads();

    // Phase B: stream x. Per group of 32 rows: wave w takes rows w*8..w*8+7.
    float acc[TYPE_N][4] = {};
    const int ng = rows / 32;
    for (int g = 0; g < ng; ++g) {
        const int lbase = g * 32 + wid * 8;
        int lb[8];
        #pragma unroll
        for (int j = 0; j < 8; ++j) lb[j] = labs[lbase + j];
        float4 v[8];
        #pragma unroll
        for (int j = 0; j < 8; ++j)
            v[j] = *reinterpret_cast<const float4*>(
                x + (size_t)(r0 + lbase + j) * D + lane * 4);
        #pragma unroll
        for (int j = 0; j < 8; ++j) {
            #pragma unroll
            for (int c = 0; c < TYPE_N; ++c) {
                const float m = (lb[j] == c) ? 1.0f : 0.0f;
                acc[c][0] = fmaf(m, v[j].x, acc[c][0]);
                acc[c][1] = fmaf(m, v[j].y, acc[c][1]);
                acc[c][2] = fmaf(m, v[j].z, acc[c][2]);
                acc[c][3] = fmaf(m, v[j].w, acc[c][3]);
            }
        }
    }
    // remainder rows: one row per wave, strided
    for (int r = ng * 32 + wid; r < rows; r += 4) {
        const int lab = labs[r];
        const float4 vv = *reinterpret_cast<const float4*>(
            x + (size_t)(r0 + r) * D + lane * 4);
        #pragma unroll
        for (int c = 0; c < TYPE_N; ++c) {
            const float m = (lab == c) ? 1.0f : 0.0f;
            acc[c][0] = fmaf(m, vv.x, acc[c][0]);
            acc[c][1] = fmaf(m, vv.y, acc[c][1]);
            acc[c][2] = fmaf(m, vv.z, acc[c][2]);
            acc[c][3] = fmaf(m, vv.w, acc[c][3]);
        }
    }

    #pragma unroll
    for (int c = 0; c < TYPE_N; ++c)
        *reinterpret_cast<float4*>(&lsum[wid][c][lane * 4]) =
            make_float4(acc[c][0], acc[c][1], acc[c][2], acc[c][3]);
    __syncthreads();

    const int t = threadIdx.x;
    float* sums = ws + (size_t)(blockIdx.x % NCOPY) * (TYPE_N * D);
    #pragma unroll
    for (int c = 0; c < TYPE_N; ++c) {
        float s = lsum[0][c][t] + lsum[1][c][t] + lsum[2][c][t] + lsum[3][c][t];
        atomicAdd(&sums[c * D + t], s);
    }
}

// --- K2: reduce copies -> centers (raw + eps-folded) ------------------------
__global__ __launch_bounds__(256) void k2_center(float* __restrict__ ws) {
    const int t = threadIdx.x;  // column 0..255
    float cnts[TYPE_N];
    #pragma unroll
    for (int c = 0; c < TYPE_N; ++c) {
        float s = 0.f;
        #pragma unroll
        for (int p = 0; p < NCOPY; ++p) s += ws[OFF_CNTP + p * TYPE_N + c];
        cnts[c] = s;
    }
    float* center = ws + OFF_CENTER;
    float* cme    = ws + OFF_CME;
    #pragma unroll
    for (int c = 0; c < TYPE_N; ++c) {
        float s = 0.f;
        #pragma unroll
        for (int p = 0; p < NCOPY; ++p) s += ws[p * TYPE_N * D + c * D + t];
        float sc = fmaxf(cnts[c], 1.0f);
        float ctr = (cnts[c] > 0.f) ? s / sc : 0.f;
        center[c * D + t] = ctr;
        cme[c * D + t]    = ctr - EPS;   // so diff = x - cme (eps folded)
    }
    if (t < TYPE_N) ws[OFF_CNTF + t] = cnts[t];
}

// --- K3: row-per-thread distance to own centroid ----------------------------
__global__ __launch_bounds__(256) void k3_dist(const float* __restrict__ x,
                                               const float* __restrict__ y,
                                               float* __restrict__ ws, int N) {
    __shared__ float lds[4][TYPE_N];
    const int lane = threadIdx.x & 63;
    const int wid  = threadIdx.x >> 6;
    const int r = blockIdx.x * 256 + threadIdx.x;

    int lab = 0;
    float d = 0.f;
    if (r < N) {
        lab = argmax5(y + (size_t)r * TYPE_N);
        const float4* xr = reinterpret_cast<const float4*>(x + (size_t)r * D);
        const float4* cr = reinterpret_cast<const float4*>(ws + OFF_CME + lab * D);
        float ss[4] = {0.f, 0.f, 0.f, 0.f};
        #pragma unroll 8
        for (int i = 0; i < 64; ++i) {
            const float4 a = xr[i];
            const float4 b = cr[i];
            const float t0 = a.x - b.x;
            const float t1 = a.y - b.y;
            const float t2 = a.z - b.z;
            const float t3 = a.w - b.w;
            float s = fmaf(t0, t0, t1 * t1);
            s = fmaf(t2, t2, s);
            s = fmaf(t3, t3, s);
            ss[i & 3] += s;
        }
        d = sqrtf(ss[0] + ss[1] + ss[2] + ss[3]);
    }

    #pragma unroll
    for (int c = 0; c < TYPE_N; ++c) {
        float v = (lab == c) ? d : 0.f;
        #pragma unroll
        for (int off = 32; off > 0; off >>= 1) v += __shfl_xor(v, off);
        if (lane == 0) lds[wid][c] = v;
    }
    __syncthreads();
    if (threadIdx.x < TYPE_N) {
        float s = lds[0][threadIdx.x] + lds[1][threadIdx.x] +
                  lds[2][threadIdx.x] + lds[3][threadIdx.x];
        atomicAdd(&ws[OFF_DSUM + (blockIdx.x % NCOPY) * TYPE_N + threadIdx.x], s);
    }
}

// --- K4: scalar epilogue -----------------------------------------------------
__global__ __launch_bounds__(64) void k4_final(const float* __restrict__ ws,
                                               float* __restrict__ out) {
    const int lane = threadIdx.x;  // 0..63
    const float* center = ws + OFF_CENTER;
    const float* counts = ws + OFF_CNTF;
    const float* dsp    = ws + OFF_DSUM;

    float csum[TYPE_N];
    #pragma unroll
    for (int c = 0; c < TYPE_N; ++c) {
        float s = 0.f;
        #pragma unroll
        for (int k = 0; k < 4; ++k) s += center[c * D + lane * 4 + k];
        #pragma unroll
        for (int off = 32; off > 0; off >>= 1) s += __shfl_xor(s, off);
        csum[c] = s;
    }

    float cnts[TYPE_N], dsum[TYPE_N];
    bool present[TYPE_N];
    float real_n = 0.f;
    #pragma unroll
    for (int c = 0; c < TYPE_N; ++c) {
        cnts[c] = counts[c];
        float s = 0.f;
        #pragma unroll
        for (int p = 0; p < NCOPY; ++p) s += dsp[p * TYPE_N + c];
        dsum[c] = s;
        present[c] = (cnts[c] > 0.f) && (csum[c] != 0.f);
        real_n += present[c] ? 1.f : 0.f;
    }

    float loss_pos = 0.f;
    #pragma unroll
    for (int c = 0; c < TYPE_N; ++c) {
        float pcm = dsum[c] / fmaxf(cnts[c], 1.f);
        loss_pos += present[c] ? pcm : 0.f;
    }
    loss_pos = (real_n > 0.f) ? loss_pos / fmaxf(real_n, 1.f) : 1.0f;

    float pairsum = 0.f;
    #pragma unroll
    for (int i = 0; i < TYPE_N; ++i) {
        #pragma unroll
        for (int j = i + 1; j < TYPE_N; ++j) {
            float s = 0.f;
            #pragma unroll
            for (int k = 0; k < 4; ++k) {
                float dd = center[i * D + lane * 4 + k] - center[j * D + lane * 4 + k] + EPS;
                s += dd * dd;
            }
            #pragma unroll
            for (int off = 32; off > 0; off >>= 1) s += __shfl_xor(s, off);
            float pd = sqrtf(s);
            pairsum += (present[i] && present[j]) ? pd : 0.f;
        }
    }
    float n_pairs = real_n * (real_n - 1.f) * 0.5f;
    float loss_neg = (real_n > 1.f) ? pairsum / fmaxf(n_pairs, 1.f) : 0.f;

    if (lane == 0) out[0] = loss_pos / (loss_neg + loss_pos);
}

extern "C" void kernel_launch(void* const* d_in, const int* in_sizes, int n_in,
                              void* d_out, int out_size, void* d_ws, size_t ws_size,
                              hipStream_t stream) {
    const float* x = (const float*)d_in[0];
    const float* y = (const float*)d_in[1];
    float* out = (float*)d_out;
    float* ws  = (float*)d_ws;
    const int N = in_sizes[0] / D;  // 200000

    hipMemsetAsync(d_ws, 0, (size_t)WS_FLOATS * sizeof(float), stream);

    const int grid1 = 1024;
    int rpb = (N + grid1 - 1) / grid1;     // 196 for N=200000
    if (rpb > 256) rpb = 256;              // labs[] capacity guard (N fixed here)
    k1_sums<<<grid1, 256, 0, stream>>>(x, y, ws, N, rpb);
    k2_center<<<1, 256, 0, stream>>>(ws);
    const int grid3 = (N + 255) / 256;     // one row per thread
    k3_dist<<<grid3, 256, 0, stream>>>(x, y, ws, N);
    k4_final<<<1, 64, 0, stream>>>(ws, out);
}